// Round 10
// baseline (116.470 us; speedup 1.0000x reference)
//
#include <hip/hip_runtime.h>

// ---------------- types & helpers ----------------
typedef __attribute__((ext_vector_type(8))) short short8;   // 8 bf16 (4 VGPRs)
typedef __attribute__((ext_vector_type(4))) float f32x4;

#define LEAKY_F 0.3f

typedef __attribute__((address_space(3))) void lds_t;
typedef __attribute__((address_space(1))) void gmem_t;
#define G2L(g, l) __builtin_amdgcn_global_load_lds((const gmem_t*)(g), (lds_t*)(l), 16, 0, 0)

__device__ __forceinline__ unsigned short f2bf(float f) {
    union { float f; unsigned u; } v; v.f = f;
    unsigned u = v.u;
    return (unsigned short)((u + 0x7fffu + ((u >> 16) & 1u)) >> 16);  // RNE
}
__device__ __forceinline__ float bf2f(unsigned short u) {
    union { unsigned u; float f; } v; v.u = ((unsigned)u) << 16; return v.f;
}

// ---------------- merged prep: cast+pad, halo zero, weight prep, avg ----------------
// grid ranges: [0,8192) cast | [8192,8224) zeroA | [8224,8240) zeroH |
//              [8240,10800) prep_w1 | [10800,12080) prep_w2 | [12080,12112) avg
__global__ __launch_bounds__(256) void prep_all(
    const float* __restrict__ x, unsigned short* __restrict__ xbp,
    unsigned short* __restrict__ h1bp,
    const float* __restrict__ w1, unsigned short* __restrict__ wr1,
    const float* __restrict__ w2, unsigned short* __restrict__ wr2,
    const float* __restrict__ target, const int* __restrict__ dr,
    float* __restrict__ outAvg)
{
    __shared__ float vcum[4097];
    __shared__ float ncum[4097];
    __shared__ float sS[256];
    __shared__ float sC[256];
    __shared__ int   sI[256];

    const int blk = blockIdx.x, tid = threadIdx.x;

    if (blk < 8192) {
        // ---- cast x f32 -> bf16 into padded [32][1028][512] ----
        int i = blk * 256 + tid;
        long g = (long)i * 8;
        int row = (int)(g >> 9);
        int b = row >> 10;
        long o = ((long)(row + (b << 2) + 2) << 9) + (g & 511);
        const float4* p = (const float4*)(x + g);
        float4 a = p[0], c = p[1];
        union { unsigned short s[8]; uint4 v; } u;
        u.s[0] = f2bf(a.x); u.s[1] = f2bf(a.y); u.s[2] = f2bf(a.z); u.s[3] = f2bf(a.w);
        u.s[4] = f2bf(c.x); u.s[5] = f2bf(c.y); u.s[6] = f2bf(c.z); u.s[7] = f2bf(c.w);
        *(uint4*)(xbp + o) = u.v;
    } else if (blk < 8240) {
        // ---- zero halo rows {0,1,1026,1027} ----
        unsigned short* p; int cin, j;
        if (blk < 8224) { p = xbp;  cin = 512; j = (blk - 8192) * 256 + tid; }
        else            { p = h1bp; cin = 256; j = (blk - 8224) * 256 + tid; }
        int upb = cin >> 1;
        int b = j / upb, rem = j % upb;
        int upr = cin >> 3;
        int r4 = rem / upr;
        int col = (rem % upr) * 8;
        int rowp = (r4 < 2) ? r4 : (r4 + 1024);
        *(uint4*)(p + ((long)b * 1028 + rowp) * cin + col) = make_uint4(0u, 0u, 0u, 0u);
    } else if (blk < 12080) {
        // ---- weight rearrange: [CH][CIN][5] -> [CH][5*CIN] bf16 ----
        const float* w; unsigned short* out; int CIN, i;
        if (blk < 10800) { w = w1; out = wr1; CIN = 512; i = (blk - 8240) * 256 + tid; }
        else             { w = w2; out = wr2; CIN = 256; i = (blk - 10800) * 256 + tid; }
        int ch = i / (CIN * 5);
        int rem = i % (CIN * 5);
        int tap = rem / CIN;
        int cin = rem % CIN;
        out[ch * (5 * CIN) + tap * CIN + cin] = f2bf(w[(ch * CIN + cin) * 5 + tap]);
    } else {
        // ---- averaged-over-durations (exact reference algorithm) ----
        int b = blk - 12080;
        const float* tb = target + b * 4096;
        float lv[16]; float ls = 0.f, lc = 0.f;
        #pragma unroll
        for (int j = 0; j < 16; j++) {
            float v = tb[tid * 16 + j]; lv[j] = v; ls += v; lc += (v != 0.f) ? 1.f : 0.f;
        }
        sS[tid] = ls; sC[tid] = lc;
        __syncthreads();
        for (int off = 1; off < 256; off <<= 1) {
            float a = 0.f, c2 = 0.f;
            if (tid >= off) { a = sS[tid - off]; c2 = sC[tid - off]; }
            __syncthreads();
            sS[tid] += a; sC[tid] += c2;
            __syncthreads();
        }
        float pS = tid ? sS[tid - 1] : 0.f, pC = tid ? sC[tid - 1] : 0.f;
        if (tid == 0) { vcum[0] = 0.f; ncum[0] = 0.f; }
        float run = pS, runc = pC;
        #pragma unroll
        for (int j = 0; j < 16; j++) {
            run += lv[j]; runc += (lv[j] != 0.f) ? 1.f : 0.f;
            vcum[tid * 16 + j + 1] = run; ncum[tid * 16 + j + 1] = runc;
        }
        const int* db = dr + b * 1024;
        int ld[4]; int lsum = 0;
        #pragma unroll
        for (int j = 0; j < 4; j++) { ld[j] = db[tid * 4 + j]; lsum += ld[j]; }
        sI[tid] = lsum;
        __syncthreads();
        for (int off = 1; off < 256; off <<= 1) {
            int a = 0; if (tid >= off) a = sI[tid - off];
            __syncthreads();
            sI[tid] += a;
            __syncthreads();
        }
        int run2 = tid ? sI[tid - 1] : 0;
        #pragma unroll
        for (int j = 0; j < 4; j++) {
            run2 += ld[j];
            int e = run2, s0 = e - ld[j];
            float sums = vcum[e] - vcum[s0];
            float cnt  = ncum[e] - ncum[s0];
            outAvg[b * 1024 + tid * 4 + j] = (cnt == 0.f) ? 0.f : sums / cnt;
        }
    }
}

// ---------------- conv-as-GEMM + fused epilogue (round-3 verified optimum) ----------------
// A padded [32][1028][CIN] bf16; im2col linear. Tile 128x256, BK=64, 8 waves
// (2Mx4N, 64x64 each). 3-deep LDS ring, counted vmcnt(6), raw barriers.
// PRED=false: epilogue = bias+leaky+LN -> padded bf16 Yln, PLUS fused
//             energy_emb (1->256 conv K=3 on avg) emission -> outEmb.
// PRED=true : epilogue = bias+leaky+LN+dot(wlin)+blin+mask -> f32 Ypred.
template<int CIN, bool PRED>
__global__ __launch_bounds__(512, 1) void gemm_conv_fused(
    const unsigned short* __restrict__ A,
    const unsigned short* __restrict__ W,    // [256][5*CIN]
    const float* __restrict__ bias,
    const float* __restrict__ gam,
    const float* __restrict__ bet,
    const float* __restrict__ wlin,
    const float* __restrict__ blin,
    const unsigned char* __restrict__ mask,
    unsigned short* __restrict__ Yln,        // [32][1028][256] padded
    float* __restrict__ Ypred,               // [32768]
    const float* __restrict__ avg,           // [32][1024]   (emb input)
    const float* __restrict__ wemb,          // [256][3]
    const float* __restrict__ bemb,          // [256]
    float* __restrict__ outEmb)              // [32][256][1024]
{
    constexpr int KW = 5 * CIN;
    constexpr int S  = KW / 64;
    constexpr int ASLOT = 128 * 64;          // elems (16 KB)
    constexpr int BSLOT = 256 * 64;          // elems (32 KB)
    __shared__ __align__(16) unsigned short smem[3 * (ASLOT + BSLOT)];  // 144 KB

    const int tid = threadIdx.x, lane = tid & 63, wid = tid >> 6;
    const int wm = wid >> 2, wn = wid & 3;
    const int blk = blockIdx.x;
    const int bb = blk >> 3, tl0 = (blk & 7) << 7;
    const long rowbase = (long)bb * 1028 + tl0;

    // staging descriptors: LDS dest linear; source seg pre-swizzled (seg ^= r&7)
    long asrc[2]; int adst[2];
    #pragma unroll
    for (int c = 0; c < 2; c++) {
        int u = ((c * 8 + wid) << 6) + lane;
        int r = u >> 3, sg = (u & 7) ^ (r & 7);
        asrc[c] = (rowbase + r) * (long)CIN + sg * 8;
        adst[c] = (c * 8 + wid) << 9;
    }
    long bsrc[4]; int bdst[4];
    #pragma unroll
    for (int c = 0; c < 4; c++) {
        int u = ((c * 8 + wid) << 6) + lane;
        int r = u >> 3, sg = (u & 7) ^ (r & 7);
        bsrc[c] = (long)r * KW + sg * 8;
        bdst[c] = (c * 8 + wid) << 9;
    }

    f32x4 acc[4][4] = {};

    auto stage = [&](int t, int slot) {
        const int k0 = t * 64;
        unsigned short* a = smem + slot * ASLOT;
        unsigned short* b = smem + 3 * ASLOT + slot * BSLOT;
        #pragma unroll
        for (int c = 0; c < 2; c++) G2L(A + asrc[c] + k0, a + adst[c]);
        #pragma unroll
        for (int c = 0; c < 4; c++) G2L(W + bsrc[c] + k0, b + bdst[c]);
    };

    const int l15 = lane & 15, lhi = (lane >> 4) & 3;
    const int arow = (wm * 64 + l15) * 64;
    const int brow = (wn * 64 + l15) * 64;
    const int sw = l15 & 7;

    auto compute = [&](int slot) {
        const unsigned short* ab = smem + slot * ASLOT;
        const unsigned short* bp = smem + 3 * ASLOT + slot * BSLOT;
        #pragma unroll
        for (int kh = 0; kh < 2; kh++) {
            short8 af[4], bg[4];
            const int sgoff = (((kh << 2) | lhi) ^ sw) << 3;
            #pragma unroll
            for (int m = 0; m < 4; m++)
                af[m] = *(const short8*)&ab[arow + m * 1024 + sgoff];
            #pragma unroll
            for (int n = 0; n < 4; n++)
                bg[n] = *(const short8*)&bp[brow + n * 1024 + sgoff];
            asm volatile("s_waitcnt lgkmcnt(0)" ::: "memory");
            __builtin_amdgcn_sched_barrier(0);
            __builtin_amdgcn_s_setprio(1);
            #pragma unroll
            for (int m = 0; m < 4; m++)
                #pragma unroll
                for (int n = 0; n < 4; n++)
                    acc[m][n] = __builtin_amdgcn_mfma_f32_16x16x32_bf16(af[m], bg[n], acc[m][n], 0, 0, 0);
            __builtin_amdgcn_s_setprio(0);
            __builtin_amdgcn_sched_barrier(0);
            if (kh == 0) __builtin_amdgcn_s_barrier();
        }
    };

    // prologue: tiles 0 and 1 in flight
    stage(0, 0);
    stage(1, 1);

    int rb = 0;
    #pragma unroll 1
    for (int t = 0; t < S - 2; ++t) {
        asm volatile("s_waitcnt vmcnt(6)" ::: "memory");
        __builtin_amdgcn_sched_barrier(0);
        __builtin_amdgcn_s_barrier();
        __builtin_amdgcn_sched_barrier(0);
        stage(t + 2, (rb == 0) ? 2 : (rb - 1));
        compute(rb);
        rb = (rb == 2) ? 0 : (rb + 1);
    }
    // t = S-2: tile S-1 still in flight
    asm volatile("s_waitcnt vmcnt(6)" ::: "memory");
    __builtin_amdgcn_sched_barrier(0);
    __builtin_amdgcn_s_barrier();
    __builtin_amdgcn_sched_barrier(0);
    compute(rb);
    rb = (rb == 2) ? 0 : (rb + 1);
    // t = S-1: drain
    asm volatile("s_waitcnt vmcnt(0)" ::: "memory");
    __builtin_amdgcn_sched_barrier(0);
    __builtin_amdgcn_s_barrier();
    __builtin_amdgcn_sched_barrier(0);
    compute(rb);

    // ---- fused energy_emb emission (conv1 only): overlaps epilogue LDS work ----
    if (!PRED) {
        const int ch  = (blk & 7) * 32 + (tid >> 4);   // 32 channels per block
        const int tq  = (tid & 15) * 64;               // 64 t per thread
        const float* ar = avg + bb * 1024;
        const float w0 = wemb[ch * 3], w1 = wemb[ch * 3 + 1], w2 = wemb[ch * 3 + 2];
        const float bbv = bemb[ch];
        float* op = outEmb + (((long)(bb << 8) | ch) << 10);
        #pragma unroll
        for (int q = 0; q < 16; q++) {
            const int t0 = tq + q * 4;
            float4 a = *(const float4*)(ar + t0);
            float am1 = (t0 > 0) ? ar[t0 - 1] : 0.f;
            float a4  = (t0 + 4 < 1024) ? ar[t0 + 4] : 0.f;
            float4 o;
            o.x = bbv + am1 * w0 + a.x * w1 + a.y * w2;
            o.y = bbv + a.x * w0 + a.y * w1 + a.z * w2;
            o.z = bbv + a.y * w0 + a.z * w1 + a.w * w2;
            o.w = bbv + a.z * w0 + a.w * w1 + a4  * w2;
            *(float4*)(op + t0) = o;
        }
    }

    // ================= fused epilogue =================
    __syncthreads();   // safe to reuse smem

    float* pb = (float*)((char*)smem + 65536);   // params: bias|gam|bet|wlin (4x256 f32)
    if (tid < 256) {
        pb[tid]       = bias[tid];
        pb[256 + tid] = gam[tid];
        pb[512 + tid] = bet[tid];
        pb[768 + tid] = PRED ? wlin[tid] : 0.f;
    }
    __syncthreads();

    // acc -> LDS tile [128][256] bf16 (bias+leaky), 16B-unit XOR swizzle
    unsigned short* tile = smem;
    #pragma unroll
    for (int n = 0; n < 4; n++) {
        const int col = wn * 64 + n * 16 + l15;
        const float bv = pb[col];
        const int u0 = col >> 3, ce = col & 7;
        #pragma unroll
        for (int m = 0; m < 4; m++) {
            const int rA = wm * 64 + m * 16 + lhi * 4;
            #pragma unroll
            for (int q = 0; q < 4; q++) {
                const int row = rA + q;
                float v = acc[m][n][q] + bv;
                v = v > 0.f ? v : LEAKY_F * v;
                tile[row * 256 + ((u0 ^ (row & 7)) << 3) + ce] = f2bf(v);
            }
        }
    }
    __syncthreads();

    // per-row reduce (4 lanes/row) & output
    const int rid = tid >> 2, jq = tid & 3;
    const int r7 = rid & 7;
    float vals[8][8];
    float s1 = 0.f, s2 = 0.f, sgw = 0.f, sgc = 0.f, sbw = 0.f;
    #pragma unroll
    for (int u4 = 0; u4 < 8; u4++) {
        const int u = u4 * 4 + jq;
        short8 pk = *(const short8*)&tile[rid * 256 + ((u ^ r7) << 3)];
        #pragma unroll
        for (int e = 0; e < 8; e++) {
            float v = bf2f((unsigned short)pk[e]);
            vals[u4][e] = v;
            s1 += v; s2 += v * v;
        }
        if (PRED) {
            const int c0 = u * 8;
            f32x4 ga = *(const f32x4*)&pb[256 + c0], gb = *(const f32x4*)&pb[260 + c0];
            f32x4 wa = *(const f32x4*)&pb[768 + c0], wb = *(const f32x4*)&pb[772 + c0];
            f32x4 ba = *(const f32x4*)&pb[512 + c0], bb2 = *(const f32x4*)&pb[516 + c0];
            #pragma unroll
            for (int e = 0; e < 4; e++) {
                sgw += vals[u4][e] * ga[e] * wa[e] + vals[u4][e + 4] * gb[e] * wb[e];
                sgc += ga[e] * wa[e] + gb[e] * wb[e];
                sbw += ba[e] * wa[e] + bb2[e] * wb[e];
            }
        }
    }
    s1 += __shfl_xor(s1, 1); s1 += __shfl_xor(s1, 2);
    s2 += __shfl_xor(s2, 1); s2 += __shfl_xor(s2, 2);
    const float mean = s1 * (1.f / 256.f);
    const float var  = s2 * (1.f / 256.f) - mean * mean;
    const float rs   = rsqrtf(var + 1e-5f);
    const long grow  = (long)blk * 128 + rid;

    if (PRED) {
        sgw += __shfl_xor(sgw, 1); sgw += __shfl_xor(sgw, 2);
        sgc += __shfl_xor(sgc, 1); sgc += __shfl_xor(sgc, 2);
        sbw += __shfl_xor(sbw, 1); sbw += __shfl_xor(sbw, 2);
        if (jq == 0) {
            float p = rs * (sgw - mean * sgc) + sbw + blin[0];
            if (mask[grow]) p = 0.f;
            Ypred[grow] = p;
        }
    } else {
        const int bnum = (int)(grow >> 10);
        const long prow = grow + (bnum << 2) + 2;
        #pragma unroll
        for (int u4 = 0; u4 < 8; u4++) {
            const int u = u4 * 4 + jq;
            const int c0 = u * 8;
            f32x4 ga = *(const f32x4*)&pb[256 + c0], gb = *(const f32x4*)&pb[260 + c0];
            f32x4 ba = *(const f32x4*)&pb[512 + c0], bb2 = *(const f32x4*)&pb[516 + c0];
            union { unsigned short s[8]; uint4 v; } o;
            #pragma unroll
            for (int e = 0; e < 4; e++) {
                o.s[e]     = f2bf((vals[u4][e]     - mean) * rs * ga[e] + ba[e]);
                o.s[e + 4] = f2bf((vals[u4][e + 4] - mean) * rs * gb[e] + bb2[e]);
            }
            *(uint4*)(Yln + prow * 256 + c0) = o.v;
        }
    }
}

// ---------------- launcher ----------------
extern "C" void kernel_launch(void* const* d_in, const int* in_sizes, int n_in,
                              void* d_out, int out_size, void* d_ws, size_t ws_size,
                              hipStream_t stream) {
    const float* x      = (const float*)d_in[0];
    const float* target = (const float*)d_in[1];
    const int*   dr     = (const int*)d_in[2];
    const unsigned char* mask = (const unsigned char*)d_in[3];
    const float* w1   = (const float*)d_in[4];
    const float* b1   = (const float*)d_in[5];
    const float* g1   = (const float*)d_in[6];
    const float* be1  = (const float*)d_in[7];
    const float* w2   = (const float*)d_in[8];
    const float* b2   = (const float*)d_in[9];
    const float* g2   = (const float*)d_in[10];
    const float* be2  = (const float*)d_in[11];
    const float* wlin = (const float*)d_in[12];
    const float* blin = (const float*)d_in[13];
    const float* wemb = (const float*)d_in[14];
    const float* bemb = (const float*)d_in[15];

    char* ws = (char*)d_ws;
    unsigned short* xbp  = (unsigned short*)ws;                    // 33,685,504 B  [32][1028][512]
    unsigned short* h1bp = (unsigned short*)(ws + 33685504);       // 16,842,752 B  [32][1028][256]
    unsigned short* wr1  = (unsigned short*)(ws + 50528256);       //  1,310,720 B
    unsigned short* wr2  = (unsigned short*)(ws + 51838976);       //    655,360 B

    float* outPred = (float*)d_out;            // 32768
    float* outAvg  = outPred + 32768;          // 32768
    float* outEmb  = outPred + 65536;          // 8,388,608

    // 1. merged prep: cast+pad x, halo zeros, weight prep, averaged target
    prep_all<<<12112, 256, 0, stream>>>(x, xbp, h1bp, w1, wr1, w2, wr2,
                                        target, dr, outAvg);
    // 2. conv1 + bias + leaky + LN1 -> padded bf16 ; fused emb -> output 2
    gemm_conv_fused<512, false><<<256, 512, 0, stream>>>(
        xbp, wr1, b1, g1, be1, wlin, blin, mask, h1bp, outPred,
        outAvg, wemb, bemb, outEmb);
    // 3. conv2 + bias + leaky + LN2 + linear + mask -> energy_pred
    gemm_conv_fused<256, true><<<256, 512, 0, stream>>>(
        h1bp, wr2, b2, g2, be2, wlin, blin, mask, h1bp, outPred,
        outAvg, wemb, bemb, outEmb);
}

// Round 13
// 113.081 us; speedup vs baseline: 1.0300x; 1.0300x over previous
//
#include <hip/hip_runtime.h>

// ---------------- types & helpers ----------------
typedef __attribute__((ext_vector_type(8))) short short8;   // 8 bf16 (4 VGPRs)
typedef __attribute__((ext_vector_type(4))) float f32x4;

#define LEAKY_F 0.3f

typedef __attribute__((address_space(3))) void lds_t;
typedef __attribute__((address_space(1))) void gmem_t;
#define G2L(g, l) __builtin_amdgcn_global_load_lds((const gmem_t*)(g), (lds_t*)(l), 16, 0, 0)

__device__ __forceinline__ unsigned short f2bf(float f) {
    union { float f; unsigned u; } v; v.f = f;
    unsigned u = v.u;
    return (unsigned short)((u + 0x7fffu + ((u >> 16) & 1u)) >> 16);  // RNE
}
__device__ __forceinline__ float bf2f(unsigned short u) {
    union { unsigned u; float f; } v; v.u = ((unsigned)u) << 16; return v.f;
}

// ---------------- merged prep: cast+pad, halo zero, weight prep, avg ----------------
// grid ranges: [0,8192) cast | [8192,8224) zeroA | [8224,8240) zeroH |
//              [8240,10800) prep_w1 | [10800,12080) prep_w2 | [12080,12112) avg
__global__ __launch_bounds__(256) void prep_all(
    const float* __restrict__ x, unsigned short* __restrict__ xbp,
    unsigned short* __restrict__ h1bp,
    const float* __restrict__ w1, unsigned short* __restrict__ wr1,
    const float* __restrict__ w2, unsigned short* __restrict__ wr2,
    const float* __restrict__ target, const int* __restrict__ dr,
    float* __restrict__ outAvg)
{
    __shared__ float vcum[4097];
    __shared__ float ncum[4097];
    __shared__ float sS[256];
    __shared__ float sC[256];
    __shared__ int   sI[256];

    const int blk = blockIdx.x, tid = threadIdx.x;

    if (blk < 8192) {
        // ---- cast x f32 -> bf16 into padded [32][1028][512] ----
        int i = blk * 256 + tid;
        long g = (long)i * 8;
        int row = (int)(g >> 9);
        int b = row >> 10;
        long o = ((long)(row + (b << 2) + 2) << 9) + (g & 511);
        const float4* p = (const float4*)(x + g);
        float4 a = p[0], c = p[1];
        union { unsigned short s[8]; uint4 v; } u;
        u.s[0] = f2bf(a.x); u.s[1] = f2bf(a.y); u.s[2] = f2bf(a.z); u.s[3] = f2bf(a.w);
        u.s[4] = f2bf(c.x); u.s[5] = f2bf(c.y); u.s[6] = f2bf(c.z); u.s[7] = f2bf(c.w);
        *(uint4*)(xbp + o) = u.v;
    } else if (blk < 8240) {
        // ---- zero halo rows {0,1,1026,1027} ----
        unsigned short* p; int cin, j;
        if (blk < 8224) { p = xbp;  cin = 512; j = (blk - 8192) * 256 + tid; }
        else            { p = h1bp; cin = 256; j = (blk - 8224) * 256 + tid; }
        int upb = cin >> 1;
        int b = j / upb, rem = j % upb;
        int upr = cin >> 3;
        int r4 = rem / upr;
        int col = (rem % upr) * 8;
        int rowp = (r4 < 2) ? r4 : (r4 + 1024);
        *(uint4*)(p + ((long)b * 1028 + rowp) * cin + col) = make_uint4(0u, 0u, 0u, 0u);
    } else if (blk < 12080) {
        // ---- weight rearrange: [CH][CIN][5] -> [CH][5*CIN] bf16 ----
        const float* w; unsigned short* out; int CIN, i;
        if (blk < 10800) { w = w1; out = wr1; CIN = 512; i = (blk - 8240) * 256 + tid; }
        else             { w = w2; out = wr2; CIN = 256; i = (blk - 10800) * 256 + tid; }
        int ch = i / (CIN * 5);
        int rem = i % (CIN * 5);
        int tap = rem / CIN;
        int cin = rem % CIN;
        out[ch * (5 * CIN) + tap * CIN + cin] = f2bf(w[(ch * CIN + cin) * 5 + tap]);
    } else {
        // ---- averaged-over-durations (exact reference algorithm) ----
        int b = blk - 12080;
        const float* tb = target + b * 4096;
        float lv[16]; float ls = 0.f, lc = 0.f;
        #pragma unroll
        for (int j = 0; j < 16; j++) {
            float v = tb[tid * 16 + j]; lv[j] = v; ls += v; lc += (v != 0.f) ? 1.f : 0.f;
        }
        sS[tid] = ls; sC[tid] = lc;
        __syncthreads();
        for (int off = 1; off < 256; off <<= 1) {
            float a = 0.f, c2 = 0.f;
            if (tid >= off) { a = sS[tid - off]; c2 = sC[tid - off]; }
            __syncthreads();
            sS[tid] += a; sC[tid] += c2;
            __syncthreads();
        }
        float pS = tid ? sS[tid - 1] : 0.f, pC = tid ? sC[tid - 1] : 0.f;
        if (tid == 0) { vcum[0] = 0.f; ncum[0] = 0.f; }
        float run = pS, runc = pC;
        #pragma unroll
        for (int j = 0; j < 16; j++) {
            run += lv[j]; runc += (lv[j] != 0.f) ? 1.f : 0.f;
            vcum[tid * 16 + j + 1] = run; ncum[tid * 16 + j + 1] = runc;
        }
        const int* db = dr + b * 1024;
        int ld[4]; int lsum = 0;
        #pragma unroll
        for (int j = 0; j < 4; j++) { ld[j] = db[tid * 4 + j]; lsum += ld[j]; }
        sI[tid] = lsum;
        __syncthreads();
        for (int off = 1; off < 256; off <<= 1) {
            int a = 0; if (tid >= off) a = sI[tid - off];
            __syncthreads();
            sI[tid] += a;
            __syncthreads();
        }
        int run2 = tid ? sI[tid - 1] : 0;
        #pragma unroll
        for (int j = 0; j < 4; j++) {
            run2 += ld[j];
            int e = run2, s0 = e - ld[j];
            float sums = vcum[e] - vcum[s0];
            float cnt  = ncum[e] - ncum[s0];
            outAvg[b * 1024 + tid * 4 + j] = (cnt == 0.f) ? 0.f : sums / cnt;
        }
    }
}

// ---------------- conv-as-GEMM + fused epilogue (round-3 verified optimum) ----------------
// A padded [32][1028][CIN] bf16; im2col linear. Tile 128x256, BK=64, 8 waves
// (2Mx4N, 64x64 each). 3-deep LDS ring, counted vmcnt(6), raw barriers.
// PRED=false: epilogue = bias+leaky+LN -> padded bf16 Yln.
// PRED=true : epilogue = bias+leaky+LN+dot(wlin)+blin+mask -> f32 Ypred.
template<int CIN, bool PRED>
__global__ __launch_bounds__(512, 1) void gemm_conv_fused(
    const unsigned short* __restrict__ A,
    const unsigned short* __restrict__ W,    // [256][5*CIN]
    const float* __restrict__ bias,
    const float* __restrict__ gam,
    const float* __restrict__ bet,
    const float* __restrict__ wlin,
    const float* __restrict__ blin,
    const unsigned char* __restrict__ mask,
    unsigned short* __restrict__ Yln,        // [32][1028][256] padded
    float* __restrict__ Ypred)               // [32768]
{
    constexpr int KW = 5 * CIN;
    constexpr int S  = KW / 64;
    constexpr int ASLOT = 128 * 64;          // elems (16 KB)
    constexpr int BSLOT = 256 * 64;          // elems (32 KB)
    __shared__ __align__(16) unsigned short smem[3 * (ASLOT + BSLOT)];  // 144 KB

    const int tid = threadIdx.x, lane = tid & 63, wid = tid >> 6;
    const int wm = wid >> 2, wn = wid & 3;
    const int blk = blockIdx.x;
    const int bb = blk >> 3, tl0 = (blk & 7) << 7;
    const long rowbase = (long)bb * 1028 + tl0;

    // staging descriptors: LDS dest linear; source seg pre-swizzled (seg ^= r&7)
    long asrc[2]; int adst[2];
    #pragma unroll
    for (int c = 0; c < 2; c++) {
        int u = ((c * 8 + wid) << 6) + lane;
        int r = u >> 3, sg = (u & 7) ^ (r & 7);
        asrc[c] = (rowbase + r) * (long)CIN + sg * 8;
        adst[c] = (c * 8 + wid) << 9;
    }
    long bsrc[4]; int bdst[4];
    #pragma unroll
    for (int c = 0; c < 4; c++) {
        int u = ((c * 8 + wid) << 6) + lane;
        int r = u >> 3, sg = (u & 7) ^ (r & 7);
        bsrc[c] = (long)r * KW + sg * 8;
        bdst[c] = (c * 8 + wid) << 9;
    }

    f32x4 acc[4][4] = {};

    auto stage = [&](int t, int slot) {
        const int k0 = t * 64;
        unsigned short* a = smem + slot * ASLOT;
        unsigned short* b = smem + 3 * ASLOT + slot * BSLOT;
        #pragma unroll
        for (int c = 0; c < 2; c++) G2L(A + asrc[c] + k0, a + adst[c]);
        #pragma unroll
        for (int c = 0; c < 4; c++) G2L(W + bsrc[c] + k0, b + bdst[c]);
    };

    const int l15 = lane & 15, lhi = (lane >> 4) & 3;
    const int arow = (wm * 64 + l15) * 64;
    const int brow = (wn * 64 + l15) * 64;
    const int sw = l15 & 7;

    auto compute = [&](int slot) {
        const unsigned short* ab = smem + slot * ASLOT;
        const unsigned short* bp = smem + 3 * ASLOT + slot * BSLOT;
        #pragma unroll
        for (int kh = 0; kh < 2; kh++) {
            short8 af[4], bg[4];
            const int sgoff = (((kh << 2) | lhi) ^ sw) << 3;
            #pragma unroll
            for (int m = 0; m < 4; m++)
                af[m] = *(const short8*)&ab[arow + m * 1024 + sgoff];
            #pragma unroll
            for (int n = 0; n < 4; n++)
                bg[n] = *(const short8*)&bp[brow + n * 1024 + sgoff];
            asm volatile("s_waitcnt lgkmcnt(0)" ::: "memory");
            __builtin_amdgcn_sched_barrier(0);
            __builtin_amdgcn_s_setprio(1);
            #pragma unroll
            for (int m = 0; m < 4; m++)
                #pragma unroll
                for (int n = 0; n < 4; n++)
                    acc[m][n] = __builtin_amdgcn_mfma_f32_16x16x32_bf16(af[m], bg[n], acc[m][n], 0, 0, 0);
            __builtin_amdgcn_s_setprio(0);
            __builtin_amdgcn_sched_barrier(0);
            if (kh == 0) __builtin_amdgcn_s_barrier();
        }
    };

    // prologue: tiles 0 and 1 in flight
    stage(0, 0);
    stage(1, 1);

    int rb = 0;
    #pragma unroll 1
    for (int t = 0; t < S - 2; ++t) {
        asm volatile("s_waitcnt vmcnt(6)" ::: "memory");
        __builtin_amdgcn_sched_barrier(0);
        __builtin_amdgcn_s_barrier();
        __builtin_amdgcn_sched_barrier(0);
        stage(t + 2, (rb == 0) ? 2 : (rb - 1));
        compute(rb);
        rb = (rb == 2) ? 0 : (rb + 1);
    }
    // t = S-2: tile S-1 still in flight
    asm volatile("s_waitcnt vmcnt(6)" ::: "memory");
    __builtin_amdgcn_sched_barrier(0);
    __builtin_amdgcn_s_barrier();
    __builtin_amdgcn_sched_barrier(0);
    compute(rb);
    rb = (rb == 2) ? 0 : (rb + 1);
    // t = S-1: drain
    asm volatile("s_waitcnt vmcnt(0)" ::: "memory");
    __builtin_amdgcn_sched_barrier(0);
    __builtin_amdgcn_s_barrier();
    __builtin_amdgcn_sched_barrier(0);
    compute(rb);

    // ================= fused epilogue =================
    __syncthreads();   // safe to reuse smem

    float* pb = (float*)((char*)smem + 65536);   // params: bias|gam|bet|wlin (4x256 f32)
    if (tid < 256) {
        pb[tid]       = bias[tid];
        pb[256 + tid] = gam[tid];
        pb[512 + tid] = bet[tid];
        pb[768 + tid] = PRED ? wlin[tid] : 0.f;
    }
    __syncthreads();

    // acc -> LDS tile [128][256] bf16 (bias+leaky), 16B-unit XOR swizzle
    unsigned short* tile = smem;
    #pragma unroll
    for (int n = 0; n < 4; n++) {
        const int col = wn * 64 + n * 16 + l15;
        const float bv = pb[col];
        const int u0 = col >> 3, ce = col & 7;
        #pragma unroll
        for (int m = 0; m < 4; m++) {
            const int rA = wm * 64 + m * 16 + lhi * 4;
            #pragma unroll
            for (int q = 0; q < 4; q++) {
                const int row = rA + q;
                float v = acc[m][n][q] + bv;
                v = v > 0.f ? v : LEAKY_F * v;
                tile[row * 256 + ((u0 ^ (row & 7)) << 3) + ce] = f2bf(v);
            }
        }
    }
    __syncthreads();

    // per-row reduce (4 lanes/row) & output
    const int rid = tid >> 2, jq = tid & 3;
    const int r7 = rid & 7;
    float vals[8][8];
    float s1 = 0.f, s2 = 0.f, sgw = 0.f, sgc = 0.f, sbw = 0.f;
    #pragma unroll
    for (int u4 = 0; u4 < 8; u4++) {
        const int u = u4 * 4 + jq;
        short8 pk = *(const short8*)&tile[rid * 256 + ((u ^ r7) << 3)];
        #pragma unroll
        for (int e = 0; e < 8; e++) {
            float v = bf2f((unsigned short)pk[e]);
            vals[u4][e] = v;
            s1 += v; s2 += v * v;
        }
        if (PRED) {
            const int c0 = u * 8;
            f32x4 ga = *(const f32x4*)&pb[256 + c0], gb = *(const f32x4*)&pb[260 + c0];
            f32x4 wa = *(const f32x4*)&pb[768 + c0], wb = *(const f32x4*)&pb[772 + c0];
            f32x4 ba = *(const f32x4*)&pb[512 + c0], bb2 = *(const f32x4*)&pb[516 + c0];
            #pragma unroll
            for (int e = 0; e < 4; e++) {
                sgw += vals[u4][e] * ga[e] * wa[e] + vals[u4][e + 4] * gb[e] * wb[e];
                sgc += ga[e] * wa[e] + gb[e] * wb[e];
                sbw += ba[e] * wa[e] + bb2[e] * wb[e];
            }
        }
    }
    s1 += __shfl_xor(s1, 1); s1 += __shfl_xor(s1, 2);
    s2 += __shfl_xor(s2, 1); s2 += __shfl_xor(s2, 2);
    const float mean = s1 * (1.f / 256.f);
    const float var  = s2 * (1.f / 256.f) - mean * mean;
    const float rs   = rsqrtf(var + 1e-5f);
    const long grow  = (long)blk * 128 + rid;

    if (PRED) {
        sgw += __shfl_xor(sgw, 1); sgw += __shfl_xor(sgw, 2);
        sgc += __shfl_xor(sgc, 1); sgc += __shfl_xor(sgc, 2);
        sbw += __shfl_xor(sbw, 1); sbw += __shfl_xor(sbw, 2);
        if (jq == 0) {
            float p = rs * (sgw - mean * sgc) + sbw + blin[0];
            if (mask[grow]) p = 0.f;
            Ypred[grow] = p;
        }
    } else {
        const int bnum = (int)(grow >> 10);
        const long prow = grow + (bnum << 2) + 2;
        #pragma unroll
        for (int u4 = 0; u4 < 8; u4++) {
            const int u = u4 * 4 + jq;
            const int c0 = u * 8;
            f32x4 ga = *(const f32x4*)&pb[256 + c0], gb = *(const f32x4*)&pb[260 + c0];
            f32x4 ba = *(const f32x4*)&pb[512 + c0], bb2 = *(const f32x4*)&pb[516 + c0];
            union { unsigned short s[8]; uint4 v; } o;
            #pragma unroll
            for (int e = 0; e < 4; e++) {
                o.s[e]     = f2bf((vals[u4][e]     - mean) * rs * ga[e] + ba[e]);
                o.s[e + 4] = f2bf((vals[u4][e + 4] - mean) * rs * gb[e] + bb2[e]);
            }
            *(uint4*)(Yln + prow * 256 + c0) = o.v;
        }
    }
}

// ---------------- energy_emb: 1->256 conv, K=3, pad 1 ----------------
__global__ void emb_kernel(const float* __restrict__ avg, const float* __restrict__ wemb,
                           const float* __restrict__ bemb, float* __restrict__ out) {
    int id = blockIdx.x * 256 + threadIdx.x;
    int t4 = id & 255;
    int ch = (id >> 8) & 255;
    int b  = id >> 16;
    int t0 = t4 * 4;
    const float* a = avg + b * 1024;
    float am1 = (t0 - 1 >= 0) ? a[t0 - 1] : 0.f;
    float a0 = a[t0], a1 = a[t0 + 1], a2 = a[t0 + 2], a3 = a[t0 + 3];
    float a4 = (t0 + 4 < 1024) ? a[t0 + 4] : 0.f;
    float w0 = wemb[ch * 3], w1 = wemb[ch * 3 + 1], w2 = wemb[ch * 3 + 2], bb = bemb[ch];
    float4 o;
    o.x = bb + am1 * w0 + a0 * w1 + a1 * w2;
    o.y = bb + a0 * w0 + a1 * w1 + a2 * w2;
    o.z = bb + a1 * w0 + a2 * w1 + a3 * w2;
    o.w = bb + a2 * w0 + a3 * w1 + a4 * w2;
    *(float4*)(out + (((b << 8) | ch) << 10) + t0) = o;
}

// ---------------- launcher ----------------
extern "C" void kernel_launch(void* const* d_in, const int* in_sizes, int n_in,
                              void* d_out, int out_size, void* d_ws, size_t ws_size,
                              hipStream_t stream) {
    const float* x      = (const float*)d_in[0];
    const float* target = (const float*)d_in[1];
    const int*   dr     = (const int*)d_in[2];
    const unsigned char* mask = (const unsigned char*)d_in[3];
    const float* w1   = (const float*)d_in[4];
    const float* b1   = (const float*)d_in[5];
    const float* g1   = (const float*)d_in[6];
    const float* be1  = (const float*)d_in[7];
    const float* w2   = (const float*)d_in[8];
    const float* b2   = (const float*)d_in[9];
    const float* g2   = (const float*)d_in[10];
    const float* be2  = (const float*)d_in[11];
    const float* wlin = (const float*)d_in[12];
    const float* blin = (const float*)d_in[13];
    const float* wemb = (const float*)d_in[14];
    const float* bemb = (const float*)d_in[15];

    char* ws = (char*)d_ws;
    unsigned short* xbp  = (unsigned short*)ws;                    // 33,685,504 B  [32][1028][512]
    unsigned short* h1bp = (unsigned short*)(ws + 33685504);       // 16,842,752 B  [32][1028][256]
    unsigned short* wr1  = (unsigned short*)(ws + 50528256);       //  1,310,720 B
    unsigned short* wr2  = (unsigned short*)(ws + 51838976);       //    655,360 B

    float* outPred = (float*)d_out;            // 32768
    float* outAvg  = outPred + 32768;          // 32768
    float* outEmb  = outPred + 65536;          // 8,388,608

    // 1. merged prep: cast+pad x, halo zeros, weight prep, averaged target
    prep_all<<<12112, 256, 0, stream>>>(x, xbp, h1bp, w1, wr1, w2, wr2,
                                        target, dr, outAvg);
    // 2. conv1 + bias + leaky + LN1 -> padded bf16
    gemm_conv_fused<512, false><<<256, 512, 0, stream>>>(
        xbp, wr1, b1, g1, be1, wlin, blin, mask, h1bp, outPred);
    // 3. conv2 + bias + leaky + LN2 + linear + mask -> energy_pred
    gemm_conv_fused<256, true><<<256, 512, 0, stream>>>(
        h1bp, wr2, b2, g2, be2, wlin, blin, mask, h1bp, outPred);
    // 4. emb conv -> output 2
    emb_kernel<<<8192, 256, 0, stream>>>(outAvg, wemb, bemb, outEmb);
}